// Round 2
// baseline (302.128 us; speedup 1.0000x reference)
//
#include <hip/hip_runtime.h>

#define NN 10000
#define NE 640000
#define DIM 128
#define CLS 40

// ---------------- CSR build ----------------

__global__ void k_degree(const int* __restrict__ dst, int* __restrict__ deg) {
    int i = blockIdx.x * blockDim.x + threadIdx.x;
    if (i < NE) atomicAdd(&deg[dst[i]], 1);
}

// single block, 256 threads: exclusive scan over deg[NN] -> row_start[NN+1]
__global__ void k_scan(const int* __restrict__ deg, int* __restrict__ row_start) {
    __shared__ int part[256];
    int t = threadIdx.x;
    const int CH = (NN + 255) / 256;  // 40
    int base = t * CH;
    int s = 0;
    for (int i = 0; i < CH; i++) {
        int idx = base + i;
        if (idx < NN) s += deg[idx];
    }
    part[t] = s;
    __syncthreads();
    // Hillis-Steele inclusive scan
    for (int off = 1; off < 256; off <<= 1) {
        int v = (t >= off) ? part[t - off] : 0;
        __syncthreads();
        part[t] += v;
        __syncthreads();
    }
    int run = (t == 0) ? 0 : part[t - 1];
    for (int i = 0; i < CH; i++) {
        int idx = base + i;
        if (idx < NN) {
            row_start[idx] = run;
            run += deg[idx];
        }
    }
    if (t == 255) row_start[NN] = part[255];
}

__global__ void k_fill(const int* __restrict__ src, const int* __restrict__ dst,
                       const int* __restrict__ row_start, int* __restrict__ cursor,
                       int* __restrict__ edge_src) {
    int i = blockIdx.x * blockDim.x + threadIdx.x;
    if (i < NE) {
        int d = dst[i];
        int p = atomicAdd(&cursor[d], 1);
        edge_src[row_start[d] + p] = src[i];
    }
}

// ---------------- mean aggregation (CSR, 1 wave per node) ----------------

__global__ void k_aggregate(const float* __restrict__ h, const int* __restrict__ row_start,
                            const int* __restrict__ edge_src, float* __restrict__ hn) {
    int node = blockIdx.x * 4 + (threadIdx.x >> 6);
    int lane = threadIdx.x & 63;
    if (node >= NN) return;
    int beg = row_start[node], end = row_start[node + 1];
    const float2* hp = (const float2*)h;
    float ax = 0.f, ay = 0.f;
    int e = beg;
    for (; e + 4 <= end; e += 4) {
        int s0 = edge_src[e + 0];
        int s1 = edge_src[e + 1];
        int s2 = edge_src[e + 2];
        int s3 = edge_src[e + 3];
        float2 v0 = hp[s0 * 64 + lane];
        float2 v1 = hp[s1 * 64 + lane];
        float2 v2 = hp[s2 * 64 + lane];
        float2 v3 = hp[s3 * 64 + lane];
        ax += v0.x + v1.x + v2.x + v3.x;
        ay += v0.y + v1.y + v2.y + v3.y;
    }
    for (; e < end; e++) {
        int s = edge_src[e];
        float2 v = hp[s * 64 + lane];
        ax += v.x;
        ay += v.y;
    }
    float degf = (float)(end - beg);
    float r = 1.0f / fmaxf(degf, 1.0f);
    float2 o;
    o.x = ax * r;
    o.y = ay * r;
    ((float2*)hn)[node * 64 + lane] = o;
}

// ---------------- fused SAGE matmul: out = act(hs@Ws + hn@Wn + b) ----------------
// 16 nodes per block, 256 threads: col = t&127, row-group = t>>7 (8 rows each)

__global__ void k_sage_mm(const float* __restrict__ hs, const float* __restrict__ hn,
                          const float* __restrict__ Ws, const float* __restrict__ Wn,
                          const float* __restrict__ b, float* __restrict__ out, int relu) {
    __shared__ float A[16][256];
    int t = threadIdx.x;
    int nb = blockIdx.x * 16;
#pragma unroll
    for (int i = 0; i < 16; i++) {
        int idx = i * 256 + t;
        int row = idx >> 8;
        int k = idx & 255;
        float v = (k < 128) ? hs[(nb + row) * 128 + k] : hn[(nb + row) * 128 + (k - 128)];
        A[row][k] = v;
    }
    __syncthreads();
    int col = t & 127;
    int rg = (t >> 7) * 8;
    float acc[8];
#pragma unroll
    for (int r = 0; r < 8; r++) acc[r] = 0.f;
#pragma unroll 8
    for (int k = 0; k < 128; k++) {
        float w = Ws[k * 128 + col];
#pragma unroll
        for (int r = 0; r < 8; r++) acc[r] += A[rg + r][k] * w;
    }
#pragma unroll 8
    for (int k = 0; k < 128; k++) {
        float w = Wn[k * 128 + col];
#pragma unroll
        for (int r = 0; r < 8; r++) acc[r] += A[rg + r][128 + k] * w;
    }
    float bias = b[col];
#pragma unroll
    for (int r = 0; r < 8; r++) {
        float v = acc[r] + bias;
        if (relu) v = fmaxf(v, 0.f);
        out[(nb + rg + r) * 128 + col] = v;
    }
}

// ---------------- classifier: out = h@Wc + bc ----------------
// 8 nodes per block, 320 threads (one output each: 8*40)

__global__ void k_classifier(const float* __restrict__ h, const float* __restrict__ Wc,
                             const float* __restrict__ bc, float* __restrict__ out) {
    __shared__ float A[8][128];
    int t = threadIdx.x;
    int nb = blockIdx.x * 8;
    for (int i = t; i < 8 * 128; i += 320) {
        int row = i >> 7, k = i & 127;
        A[row][k] = h[(nb + row) * 128 + k];
    }
    __syncthreads();
    int row = t / 40, col = t % 40;
    float acc = 0.f;
#pragma unroll 8
    for (int k = 0; k < 128; k++) acc += A[row][k] * Wc[k * 40 + col];
    out[(nb + row) * 40 + col] = acc + bc[col];
}

// ---------------- launch ----------------

static inline size_t align_up(size_t x, size_t a) { return (x + a - 1) & ~(a - 1); }

extern "C" void kernel_launch(void* const* d_in, const int* in_sizes, int n_in,
                              void* d_out, int out_size, void* d_ws, size_t ws_size,
                              hipStream_t stream) {
    const float* features = (const float*)d_in[0];
    const int* edge_index = (const int*)d_in[1];
    const float* Ws1 = (const float*)d_in[2];
    const float* Wn1 = (const float*)d_in[3];
    const float* b1 = (const float*)d_in[4];
    const float* Ws2 = (const float*)d_in[5];
    const float* Wn2 = (const float*)d_in[6];
    const float* b2 = (const float*)d_in[7];
    const float* Wc = (const float*)d_in[8];
    const float* bc = (const float*)d_in[9];
    float* out = (float*)d_out;

    const int* e_src = edge_index;
    const int* e_dst = edge_index + NE;

    char* ws = (char*)d_ws;
    size_t off = 0;
    int* deg = (int*)(ws + off);       off = align_up(off + NN * 4, 512);
    int* cursor = (int*)(ws + off);    off = align_up(off + NN * 4, 512);
    int* row_start = (int*)(ws + off); off = align_up(off + (NN + 1) * 4, 512);
    int* edge_srcb = (int*)(ws + off); off = align_up(off + (size_t)NE * 4, 512);
    float* hn = (float*)(ws + off);    off = align_up(off + (size_t)NN * DIM * 4, 512);
    float* h1 = (float*)(ws + off);    off = align_up(off + (size_t)NN * DIM * 4, 512);
    float* h2 = (float*)(ws + off);    off = align_up(off + (size_t)NN * DIM * 4, 512);

    hipMemsetAsync(deg, 0, NN * 4, stream);
    hipMemsetAsync(cursor, 0, NN * 4, stream);

    // CSR build
    k_degree<<<(NE + 255) / 256, 256, 0, stream>>>(e_dst, deg);
    k_scan<<<1, 256, 0, stream>>>(deg, row_start);
    k_fill<<<(NE + 255) / 256, 256, 0, stream>>>(e_src, e_dst, row_start, cursor, edge_srcb);

    // layer 1
    k_aggregate<<<NN / 4, 256, 0, stream>>>(features, row_start, edge_srcb, hn);
    k_sage_mm<<<NN / 16, 256, 0, stream>>>(features, hn, Ws1, Wn1, b1, h1, 1);

    // layer 2
    k_aggregate<<<NN / 4, 256, 0, stream>>>(h1, row_start, edge_srcb, hn);
    k_sage_mm<<<NN / 16, 256, 0, stream>>>(h1, hn, Ws2, Wn2, b2, h2, 1);

    // classifier
    k_classifier<<<NN / 8, 320, 0, stream>>>(h2, Wc, bc, out);
}

// Round 3
// 255.707 us; speedup vs baseline: 1.1815x; 1.1815x over previous
//
#include <hip/hip_runtime.h>

#define NN 10000
#define NE 640000
#define DIM 128
#define CLS 40

// ---------------- CSR build ----------------

// pos[i] = position of edge i within its dst bucket (atomic returns old count)
__global__ void k_degree(const int* __restrict__ dst, int* __restrict__ deg,
                         int* __restrict__ pos) {
    int i = blockIdx.x * blockDim.x + threadIdx.x;
    if (i < NE) pos[i] = atomicAdd(&deg[dst[i]], 1);
}

// single block, 1024 threads: exclusive scan deg[NN] -> row_start[NN+1], LDS-staged
__global__ void k_scan(const int* __restrict__ deg, int* __restrict__ row_start) {
    __shared__ int sdeg[10240];
    __shared__ int wsum[16];
    int t = threadIdx.x;  // 0..1023
    for (int i = t; i < 10240; i += 1024) sdeg[i] = (i < NN) ? deg[i] : 0;
    __syncthreads();
    int base = t * 10;
    int tmp[10];
    int s = 0;
#pragma unroll
    for (int i = 0; i < 10; i++) { tmp[i] = sdeg[base + i]; s += tmp[i]; }
    // wave inclusive scan
    int lane = t & 63, wid = t >> 6;
    int v = s;
#pragma unroll
    for (int off = 1; off < 64; off <<= 1) {
        int u = __shfl_up(v, off, 64);
        if (lane >= off) v += u;
    }
    if (lane == 63) wsum[wid] = v;
    __syncthreads();
    if (wid == 0) {
        int w = (lane < 16) ? wsum[lane] : 0;
#pragma unroll
        for (int off = 1; off < 16; off <<= 1) {
            int u = __shfl_up(w, off, 64);
            if (lane >= off) w += u;
        }
        if (lane < 16) wsum[lane] = w;
    }
    __syncthreads();
    int excl = v - s + ((wid > 0) ? wsum[wid - 1] : 0);
    int run = excl;
#pragma unroll
    for (int i = 0; i < 10; i++) { sdeg[base + i] = run; run += tmp[i]; }
    __syncthreads();
    for (int i = t; i < NN; i += 1024) row_start[i] = sdeg[i];
    if (t == 1023) row_start[NN] = run;  // total (tail chunks are all zero)
}

// no atomics: deterministic slot = row_start[dst] + pos
__global__ void k_fill(const int* __restrict__ src, const int* __restrict__ dst,
                       const int* __restrict__ pos, const int* __restrict__ row_start,
                       int* __restrict__ edge_src) {
    int i = blockIdx.x * blockDim.x + threadIdx.x;
    if (i < NE) {
        int p = row_start[dst[i]] + pos[i];
        __builtin_nontemporal_store(src[i], &edge_src[p]);
    }
}

// ---------------- mean aggregation (CSR, 1 wave per node, 2 edges/instr) ----------------

__global__ void k_aggregate(const float* __restrict__ h, const int* __restrict__ row_start,
                            const int* __restrict__ edge_src, float* __restrict__ hn) {
    int node = blockIdx.x * 4 + (threadIdx.x >> 6);
    int lane = threadIdx.x & 63;
    int half = lane >> 5;   // which edge of the pair this half-wave handles
    int l32 = lane & 31;    // float4 index within the 128-float row
    if (node >= NN) return;
    int beg = row_start[node], end = row_start[node + 1];
    const float4* hp = (const float4*)h;
    float ax = 0.f, ay = 0.f, az = 0.f, aw = 0.f;
    int e = beg;
    for (; e + 4 <= end; e += 4) {
        int s0 = edge_src[e + half];
        int s1 = edge_src[e + 2 + half];
        float4 v0 = hp[s0 * 32 + l32];
        float4 v1 = hp[s1 * 32 + l32];
        ax += v0.x + v1.x;
        ay += v0.y + v1.y;
        az += v0.z + v1.z;
        aw += v0.w + v1.w;
    }
    for (; e + 2 <= end; e += 2) {
        int s = edge_src[e + half];
        float4 v = hp[s * 32 + l32];
        ax += v.x; ay += v.y; az += v.z; aw += v.w;
    }
    if (e < end && half == 0) {
        int s = edge_src[e];
        float4 v = hp[s * 32 + l32];
        ax += v.x; ay += v.y; az += v.z; aw += v.w;
    }
    // combine the two half-waves (all lanes execute)
    ax += __shfl_xor(ax, 32, 64);
    ay += __shfl_xor(ay, 32, 64);
    az += __shfl_xor(az, 32, 64);
    aw += __shfl_xor(aw, 32, 64);
    if (half == 0) {
        float degf = (float)(end - beg);
        float r = 1.0f / fmaxf(degf, 1.0f);
        float4 o;
        o.x = ax * r; o.y = ay * r; o.z = az * r; o.w = aw * r;
        ((float4*)hn)[node * 32 + l32] = o;
    }
}

// ---------------- fused SAGE matmul: out = relu(hs@Ws + hn@Wn + b) ----------------
// 16 nodes per block, 256 threads: col = t&127, row-group = t>>7 (8 rows each)

__global__ void k_sage_mm(const float* __restrict__ hs, const float* __restrict__ hn,
                          const float* __restrict__ Ws, const float* __restrict__ Wn,
                          const float* __restrict__ b, float* __restrict__ out) {
    __shared__ float A[16][256];
    int t = threadIdx.x;
    int nb = blockIdx.x * 16;
#pragma unroll
    for (int i = 0; i < 16; i++) {
        int idx = i * 256 + t;
        int row = idx >> 8;
        int k = idx & 255;
        float v = (k < 128) ? hs[(nb + row) * 128 + k] : hn[(nb + row) * 128 + (k - 128)];
        A[row][k] = v;
    }
    __syncthreads();
    int col = t & 127;
    int rg = (t >> 7) * 8;
    float acc[8];
#pragma unroll
    for (int r = 0; r < 8; r++) acc[r] = 0.f;
#pragma unroll 8
    for (int k = 0; k < 128; k++) {
        float w = Ws[k * 128 + col];
#pragma unroll
        for (int r = 0; r < 8; r++) acc[r] += A[rg + r][k] * w;
    }
#pragma unroll 8
    for (int k = 0; k < 128; k++) {
        float w = Wn[k * 128 + col];
#pragma unroll
        for (int r = 0; r < 8; r++) acc[r] += A[rg + r][128 + k] * w;
    }
    float bias = b[col];
#pragma unroll
    for (int r = 0; r < 8; r++) {
        out[(nb + rg + r) * 128 + col] = fmaxf(acc[r] + bias, 0.f);
    }
}

// ---------------- layer-2 matmul fused with classifier ----------------
// h2 = relu(hs@Ws + hn@Wn + b) kept in LDS; out = h2@Wc + bc

__global__ void k_sage_mm_cls(const float* __restrict__ hs, const float* __restrict__ hn,
                              const float* __restrict__ Ws, const float* __restrict__ Wn,
                              const float* __restrict__ b, const float* __restrict__ Wc,
                              const float* __restrict__ bc, float* __restrict__ out) {
    __shared__ float A[16][256];
    __shared__ float H[16][128];
    int t = threadIdx.x;
    int nb = blockIdx.x * 16;
#pragma unroll
    for (int i = 0; i < 16; i++) {
        int idx = i * 256 + t;
        int row = idx >> 8;
        int k = idx & 255;
        float v = (k < 128) ? hs[(nb + row) * 128 + k] : hn[(nb + row) * 128 + (k - 128)];
        A[row][k] = v;
    }
    __syncthreads();
    int col = t & 127;
    int rg = (t >> 7) * 8;
    float acc[8];
#pragma unroll
    for (int r = 0; r < 8; r++) acc[r] = 0.f;
#pragma unroll 8
    for (int k = 0; k < 128; k++) {
        float w = Ws[k * 128 + col];
#pragma unroll
        for (int r = 0; r < 8; r++) acc[r] += A[rg + r][k] * w;
    }
#pragma unroll 8
    for (int k = 0; k < 128; k++) {
        float w = Wn[k * 128 + col];
#pragma unroll
        for (int r = 0; r < 8; r++) acc[r] += A[rg + r][128 + k] * w;
    }
    float bias = b[col];
#pragma unroll
    for (int r = 0; r < 8; r++) {
        H[rg + r][col] = fmaxf(acc[r] + bias, 0.f);
    }
    __syncthreads();
    // classifier: 16*40 = 640 outputs over 256 threads
    for (int o = t; o < 16 * CLS; o += 256) {
        int row = o / CLS;
        int c = o - row * CLS;
        float s = bc[c];
#pragma unroll 8
        for (int k = 0; k < 128; k++) s += H[row][k] * Wc[k * CLS + c];
        out[(nb + row) * CLS + c] = s;
    }
}

// ---------------- launch ----------------

static inline size_t align_up(size_t x, size_t a) { return (x + a - 1) & ~(a - 1); }

extern "C" void kernel_launch(void* const* d_in, const int* in_sizes, int n_in,
                              void* d_out, int out_size, void* d_ws, size_t ws_size,
                              hipStream_t stream) {
    const float* features = (const float*)d_in[0];
    const int* edge_index = (const int*)d_in[1];
    const float* Ws1 = (const float*)d_in[2];
    const float* Wn1 = (const float*)d_in[3];
    const float* b1 = (const float*)d_in[4];
    const float* Ws2 = (const float*)d_in[5];
    const float* Wn2 = (const float*)d_in[6];
    const float* b2 = (const float*)d_in[7];
    const float* Wc = (const float*)d_in[8];
    const float* bc = (const float*)d_in[9];
    float* out = (float*)d_out;

    const int* e_src = edge_index;
    const int* e_dst = edge_index + NE;

    char* ws = (char*)d_ws;
    size_t off = 0;
    int* deg = (int*)(ws + off);       off = align_up(off + NN * 4, 512);
    int* pos = (int*)(ws + off);       off = align_up(off + (size_t)NE * 4, 512);
    int* row_start = (int*)(ws + off); off = align_up(off + (NN + 1) * 4, 512);
    int* edge_srcb = (int*)(ws + off); off = align_up(off + (size_t)NE * 4, 512);
    float* hn = (float*)(ws + off);    off = align_up(off + (size_t)NN * DIM * 4, 512);
    float* h1 = (float*)(ws + off);    off = align_up(off + (size_t)NN * DIM * 4, 512);

    hipMemsetAsync(deg, 0, NN * 4, stream);

    // CSR build
    k_degree<<<NE / 256, 256, 0, stream>>>(e_dst, deg, pos);
    k_scan<<<1, 1024, 0, stream>>>(deg, row_start);
    k_fill<<<NE / 256, 256, 0, stream>>>(e_src, e_dst, pos, row_start, edge_srcb);

    // layer 1
    k_aggregate<<<NN / 4, 256, 0, stream>>>(features, row_start, edge_srcb, hn);
    k_sage_mm<<<NN / 16, 256, 0, stream>>>(features, hn, Ws1, Wn1, b1, h1);

    // layer 2
    k_aggregate<<<NN / 4, 256, 0, stream>>>(h1, row_start, edge_srcb, hn);
    k_sage_mm_cls<<<NN / 16, 256, 0, stream>>>(h1, hn, Ws2, Wn2, b2, Wc, bc, out);
}